// Round 6
// baseline (2254.622 us; speedup 1.0000x reference)
//
#include <hip/hip_runtime.h>

typedef unsigned short u16;
typedef __attribute__((ext_vector_type(8))) short short8;
typedef __attribute__((ext_vector_type(4))) short short4v;
typedef __attribute__((ext_vector_type(4))) float f32x4;

#define NSTEP 24

__device__ __forceinline__ float b2f(u16 u){ return __uint_as_float(((unsigned)u)<<16); }
__device__ __forceinline__ u16 f2b(float f){
  unsigned u = __float_as_uint(f);
  u += 0x7fffu + ((u>>16)&1u);
  return (u16)(u>>16);
}
__device__ __forceinline__ float tanh_fast(float x){
  x = fminf(12.f, fmaxf(-12.f, x));
  float e = __expf(2.f*x);
  return __fdividef(e-1.f, e+1.f);
}
__device__ __forceinline__ float sigmoid_fast(float x){
  return __fdividef(1.f, 1.f + __expf(-x));
}

// ---------------- f32 -> bf16 bulk convert ----------------
__global__ __launch_bounds__(256) void k_cvt(const float* __restrict__ in, u16* __restrict__ out, int n){
  int i = (blockIdx.x*256 + threadIdx.x)*4;
  if (i >= n) return;
  float4 v = *(const float4*)(in + i);
  short4v o;
  o[0] = (short)f2b(v.x); o[1] = (short)f2b(v.y); o[2] = (short)f2b(v.z); o[3] = (short)f2b(v.w);
  *(short4v*)(out + i) = o;
}

// ---------------- transpose 512x512, f32 in -> bf16 out ----------------
__global__ __launch_bounds__(256) void k_transpose512(const float* __restrict__ in, u16* __restrict__ out){
  __shared__ float tile[32][33];
  int tx = threadIdx.x, ty = threadIdx.y;
  int x = blockIdx.x*32 + tx;
  #pragma unroll
  for (int j=0;j<4;++j){
    int y = blockIdx.y*32 + ty + j*8;
    tile[ty+j*8][tx] = in[y*512 + x];
  }
  __syncthreads();
  int x2 = blockIdx.y*32 + tx;
  #pragma unroll
  for (int j=0;j<4;++j){
    int y2 = blockIdx.x*32 + ty + j*8;
    out[y2*512 + x2] = f2b(tile[tx][ty+j*8]);
  }
}

// ---------------- init h ----------------
__global__ __launch_bounds__(256) void k_init(const float* __restrict__ h0, float* __restrict__ hf, u16* __restrict__ xcat){
  int idx = blockIdx.x*256 + threadIdx.x;     // < 32768
  float v = h0[idx];
  hf[idx] = v;
  xcat[(idx>>9)*1024 + 512 + (idx&511)] = f2b(v);
}

// ---------------- enc_proj = encB @ WeT^T  (MFMA), bf16 out ----------------
// grid (256,4), block 256. block tile 128x128, wave tile 64x64. K-loop fully
// unrolled so the compiler can hoist loads and software-pipeline (was 9% MfmaUtil).
__global__ __launch_bounds__(256) void k_encproj(const u16* __restrict__ A, const u16* __restrict__ BT, u16* __restrict__ C){
  int w = threadIdx.x>>6, lane = threadIdx.x&63;
  int m0 = blockIdx.x*128 + (w>>1)*64;
  int n0 = blockIdx.y*128 + (w&1)*64;
  int r16 = lane&15, kof = (lane>>4)<<3;
  const u16* Ap = A + (m0+r16)*512 + kof;
  const u16* Bp = BT + (n0+r16)*512 + kof;
  f32x4 acc[4][4];
  #pragma unroll
  for (int i=0;i<4;++i)
    #pragma unroll
    for (int j=0;j<4;++j) acc[i][j] = (f32x4){0.f,0.f,0.f,0.f};
  #pragma unroll
  for (int k0=0;k0<512;k0+=32){
    short8 a[4], b[4];
    #pragma unroll
    for (int mf=0;mf<4;++mf) a[mf] = *(const short8*)(Ap + mf*16*512 + k0);
    #pragma unroll
    for (int nf=0;nf<4;++nf) b[nf] = *(const short8*)(Bp + nf*16*512 + k0);
    #pragma unroll
    for (int mf=0;mf<4;++mf)
      #pragma unroll
      for (int nf=0;nf<4;++nf)
        acc[mf][nf] = __builtin_amdgcn_mfma_f32_16x16x32_bf16(a[mf], b[nf], acc[mf][nf], 0,0,0);
  }
  int rb = (lane>>4)<<2;
  #pragma unroll
  for (int mf=0;mf<4;++mf)
    #pragma unroll
    for (int nf=0;nf<4;++nf)
      #pragma unroll
      for (int r=0;r<4;++r)
        C[(m0+mf*16+rb+r)*512 + n0+nf*16+r16] = f2b(acc[mf][nf][r]);
}

// ---------------- small GEMM tile: C[16x64 at widx] = A(64xK)bf16 @ BT^T + bias / += ----------------
__device__ __forceinline__ void gemm_bt_core(const u16* A, int lda, const u16* BT, int ldb,
    const float* bias, float* C, int ldc, int K, int widx, bool accum){
  int lane = threadIdx.x & 63;
  int mt = widx & 3, nt = widx >> 2;
  int m0 = mt<<4, n0 = nt<<6;
  int r16 = lane&15, kof = (lane>>4)<<3;
  const u16* Ap = A + (m0+r16)*lda + kof;
  const u16* Bp = BT + (n0+r16)*ldb + kof;
  f32x4 acc[4];
  #pragma unroll
  for (int i=0;i<4;++i) acc[i] = (f32x4){0.f,0.f,0.f,0.f};
  #pragma unroll 4
  for (int k0=0;k0<K;k0+=32){
    short8 a = *(const short8*)(Ap + k0);
    #pragma unroll
    for (int nf=0;nf<4;++nf){
      short8 b = *(const short8*)(Bp + nf*16*ldb + k0);
      acc[nf] = __builtin_amdgcn_mfma_f32_16x16x32_bf16(a, b, acc[nf], 0,0,0);
    }
  }
  int rb = (lane>>4)<<2;
  #pragma unroll
  for (int nf=0;nf<4;++nf){
    int col = n0 + nf*16 + r16;
    float bv = bias ? bias[col] : 0.f;
    #pragma unroll
    for (int r=0;r<4;++r){
      float* p = &C[(m0+rb+r)*ldc + col];
      float v = acc[nf][r] + bv;
      if (accum) v += *p;
      *p = v;
    }
  }
}

// ---------------- fused: scores (blocks 0..2047) || gh GEMM (2048..2071) || gi_h GEMM (2072..2095) ----------------
// score: block = (b = bid>>5, sq = bid&31), wave handles 4 s-rows, all 4 preloaded.
__global__ __launch_bounds__(256) void k_sgh(const u16* __restrict__ ep, const float* __restrict__ q,
    const float* __restrict__ av, const u16* __restrict__ xcat,
    const u16* __restrict__ WhhB, const float* __restrict__ bhh,
    const u16* __restrict__ WihB, const float* __restrict__ bih,
    float* __restrict__ sc, float* __restrict__ gh, float* __restrict__ gi){
  int bid = blockIdx.x, tid = threadIdx.x;
  int wid = tid>>6, lane = tid&63;
  if (bid < 2048){
    int b = bid >> 5, sq = bid & 31;
    float qv[8], vv[8];
    {
      float4 q0 = *(const float4*)(q + b*512 + lane*8);
      float4 q1 = *(const float4*)(q + b*512 + lane*8 + 4);
      qv[0]=q0.x; qv[1]=q0.y; qv[2]=q0.z; qv[3]=q0.w;
      qv[4]=q1.x; qv[5]=q1.y; qv[6]=q1.z; qv[7]=q1.w;
      float4 v0 = *(const float4*)(av + lane*8);
      float4 v1 = *(const float4*)(av + lane*8 + 4);
      vv[0]=v0.x; vv[1]=v0.y; vv[2]=v0.z; vv[3]=v0.w;
      vv[4]=v1.x; vv[5]=v1.y; vv[6]=v1.z; vv[7]=v1.w;
    }
    int srow = sq*16 + wid*4;
    const u16* base = ep + (b*512 + srow)*512 + lane*8;
    short8 e0 = *(const short8*)(base);
    short8 e1 = *(const short8*)(base + 512);
    short8 e2 = *(const short8*)(base + 1024);
    short8 e3 = *(const short8*)(base + 1536);
    float r0=0.f, r1=0.f, r2=0.f, r3=0.f;
    #pragma unroll
    for (int j=0;j<8;++j){
      r0 += vv[j]*tanh_fast(b2f((u16)e0[j]) + qv[j]);
      r1 += vv[j]*tanh_fast(b2f((u16)e1[j]) + qv[j]);
      r2 += vv[j]*tanh_fast(b2f((u16)e2[j]) + qv[j]);
      r3 += vv[j]*tanh_fast(b2f((u16)e3[j]) + qv[j]);
    }
    #pragma unroll
    for (int off=32; off; off>>=1){
      r0 += __shfl_xor(r0, off);
      r1 += __shfl_xor(r1, off);
      r2 += __shfl_xor(r2, off);
      r3 += __shfl_xor(r3, off);
    }
    if (lane==0){
      sc[b*512 + srow]   = r0;
      sc[b*512 + srow+1] = r1;
      sc[b*512 + srow+2] = r2;
      sc[b*512 + srow+3] = r3;
    }
  } else if (bid < 2072){
    gemm_bt_core(xcat+512, 1024, WhhB, 512, bhh, gh, 1536, 512, (bid-2048)*4 + wid, false);
  } else {
    gemm_bt_core(xcat+512, 1024, WihB+512, 1024, bih, gi, 1536, 512, (bid-2072)*4 + wid, false);
  }
}

// ---------------- softmax + context h-chunk -> xcat[:, hc*128..+128], grid (4,64) ----------------
__global__ __launch_bounds__(256) void k_ctx(const float* __restrict__ sc, const u16* __restrict__ encB,
    u16* __restrict__ xcat){
  __shared__ float red[256];
  __shared__ float al[512];
  __shared__ float part[16][128];
  int t = threadIdx.x, hc = blockIdx.x, b = blockIdx.y;
  float s1 = sc[b*512 + t], s2 = sc[b*512 + 256 + t];
  red[t] = fmaxf(s1, s2); __syncthreads();
  for (int off=128; off; off>>=1){ if (t<off) red[t] = fmaxf(red[t], red[t+off]); __syncthreads(); }
  float mx = red[0]; __syncthreads();
  float e1 = __expf(s1-mx), e2 = __expf(s2-mx);
  red[t] = e1+e2; __syncthreads();
  for (int off=128; off; off>>=1){ if (t<off) red[t] += red[t+off]; __syncthreads(); }
  float inv = __fdividef(1.f, red[0]);
  al[t] = e1*inv; al[t+256] = e2*inv;
  __syncthreads();
  // thread (cg = t&15, sg = t>>4): cols hc*128 + cg*8 .. +8, s in [sg*32, +32)
  int cg = t & 15, sg = t >> 4;
  const u16* eb = encB + (b*512 + sg*32)*512 + hc*128 + cg*8;
  const float* alp = al + sg*32;
  float a8[8];
  #pragma unroll
  for (int j=0;j<8;++j) a8[j] = 0.f;
  #pragma unroll 8
  for (int s=0;s<32;++s){
    short8 e = *(const short8*)(eb + s*512);
    float a = alp[s];
    #pragma unroll
    for (int j=0;j<8;++j) a8[j] = fmaf(a, b2f((u16)e[j]), a8[j]);
  }
  #pragma unroll
  for (int j=0;j<8;++j) part[sg][cg*8+j] = a8[j];
  __syncthreads();
  if (t < 128){
    float v = 0.f;
    #pragma unroll
    for (int sg2=0;sg2<16;++sg2) v += part[sg2][t];
    xcat[b*1024 + hc*128 + t] = f2b(v);
  }
}

// ---------------- gi += ctx @ Wih[:, :512]^T  (24 blocks) ----------------
__global__ __launch_bounds__(256) void k_gictx(const u16* __restrict__ xcat, const u16* __restrict__ WihB,
    float* __restrict__ gi){
  int widx = blockIdx.x*4 + (threadIdx.x>>6);
  gemm_bt_core(xcat, 1024, WihB, 1024, (const float*)0, gi, 1536, 512, widx, true);
}

// ---------------- q[j] = ab[j] + sum_k hl[k]*WdT[j][k], 2 outputs per thread ----------------
__device__ __forceinline__ void q_core(const float* hl, const u16* WdT, const float* ab, float* qrow){
  int tid = threadIdx.x;
  #pragma unroll
  for (int jj=0;jj<2;++jj){
    int j = tid + jj*256;
    float acc = ab[j];
    const u16* wr = WdT + j*512;
    #pragma unroll 4
    for (int k0=0;k0<512;k0+=8){
      short8 wv = *(const short8*)(wr + k0);
      #pragma unroll
      for (int i=0;i<8;++i) acc = fmaf(hl[k0+i], b2f((u16)wv[i]), acc);
    }
    qrow[j] = acc;
  }
}

// ---------------- q(0) from h0 ----------------
__global__ __launch_bounds__(256) void k_q0(const float* __restrict__ hf, const u16* __restrict__ WdT,
    const float* __restrict__ ab, float* __restrict__ q){
  __shared__ float hl[512];
  int t = threadIdx.x, b = blockIdx.x;
  hl[t] = hf[b*512 + t];
  hl[t+256] = hf[b*512 + 256 + t];
  __syncthreads();
  q_core(hl, WdT, ab, q + b*512);
}

// ---------------- fin: gates + head + next q, one block per b ----------------
__global__ __launch_bounds__(256) void k_fin(const float* __restrict__ gi, const float* __restrict__ gh,
    const float* __restrict__ lng, const float* __restrict__ lnb,
    const float* __restrict__ W1, const float* __restrict__ b1,
    const float* __restrict__ W2, const float* __restrict__ b2,
    const u16* __restrict__ WdT, const float* __restrict__ ab,
    float* __restrict__ hf, u16* __restrict__ xcat, float* __restrict__ q,
    float* __restrict__ out, int step){
  __shared__ float hl[512];
  __shared__ float yn[512];
  __shared__ float red[256];
  int tid = threadIdx.x, b = blockIdx.x;
  #pragma unroll
  for (int jj=0;jj<2;++jj){
    int n = tid + jj*256;
    int gb = b*1536 + n;
    float r  = sigmoid_fast(gi[gb]      + gh[gb]);
    float z  = sigmoid_fast(gi[gb+512]  + gh[gb+512]);
    float nn = tanh_fast(gi[gb+1024] + r*gh[gb+1024]);
    float hp = hf[b*512 + n];
    float hnew = (1.f-z)*nn + z*hp;
    hf[b*512 + n] = hnew;
    xcat[b*1024 + 512 + n] = f2b(hnew);
    hl[n] = hnew;
    if (step == NSTEP-1) out[1536 + b*512 + n] = hnew;
  }
  __syncthreads();
  float h1 = hl[tid], h2 = hl[tid+256];
  red[tid] = h1+h2; __syncthreads();
  for (int off=128; off; off>>=1){ if (tid<off) red[tid]+=red[tid+off]; __syncthreads(); }
  float mu = red[0]*(1.f/512.f); __syncthreads();
  red[tid] = h1*h1+h2*h2; __syncthreads();
  for (int off=128; off; off>>=1){ if (tid<off) red[tid]+=red[tid+off]; __syncthreads(); }
  float var = red[0]*(1.f/512.f) - mu*mu; __syncthreads();
  float rs = rsqrtf(var + 1e-5f);
  yn[tid]     = (h1-mu)*rs*lng[tid] + lnb[tid];
  yn[tid+256] = (h2-mu)*rs*lng[tid+256] + lnb[tid+256];
  __syncthreads();
  float acc = b1[tid];
  #pragma unroll 8
  for (int k=0;k<512;++k) acc = fmaf(yn[k], W1[k*256+tid], acc);
  float y = fmaxf(acc, 0.f);
  red[tid] = y*W2[tid]; __syncthreads();
  for (int off=128; off; off>>=1){ if (tid<off) red[tid]+=red[tid+off]; __syncthreads(); }
  if (tid==0) out[b*24 + step] = red[0] + b2[0];
  if (step < NSTEP-1){
    __syncthreads();
    q_core(hl, WdT, ab, q + b*512);   // hl still holds h_new
  }
}

extern "C" void kernel_launch(void* const* d_in, const int* in_sizes, int n_in,
                              void* d_out, int out_size, void* d_ws, size_t ws_size,
                              hipStream_t stream){
  (void)in_sizes; (void)n_in; (void)out_size; (void)ws_size;
  const float* enc = (const float*)d_in[0];
  const float* h0  = (const float*)d_in[1];
  const float* We  = (const float*)d_in[2];
  const float* Wd  = (const float*)d_in[3];
  const float* ab  = (const float*)d_in[4];
  const float* av  = (const float*)d_in[5];
  const float* Wih = (const float*)d_in[6];
  const float* Whh = (const float*)d_in[7];
  const float* bih = (const float*)d_in[8];
  const float* bhh = (const float*)d_in[9];
  const float* lng = (const float*)d_in[10];
  const float* lnb = (const float*)d_in[11];
  const float* W1  = (const float*)d_in[12];
  const float* b1  = (const float*)d_in[13];
  const float* W2  = (const float*)d_in[14];
  const float* b2  = (const float*)d_in[15];
  float* out = (float*)d_out;
  char* ws = (char*)d_ws;
  u16*  ep   = (u16*)(ws + 0);          // 33,554,432
  u16*  encB = (u16*)(ws + 33554432);   // 33,554,432
  u16*  WeT  = (u16*)(ws + 67108864);   //    524,288
  u16*  WdT  = (u16*)(ws + 67633152);   //    524,288
  u16*  WihB = (u16*)(ws + 68157440);   //  3,145,728
  u16*  WhhB = (u16*)(ws + 71303168);   //  1,572,864
  float* hf  = (float*)(ws + 72876032); //    131,072
  u16*  xcat = (u16*)(ws + 73007104);   //    131,072  [ctx(512); h(512)] bf16 per b
  float* q   = (float*)(ws + 73138176); //    131,072
  float* sc  = (float*)(ws + 73269248); //    131,072
  float* gi  = (float*)(ws + 73400320); //    393,216
  float* gh  = (float*)(ws + 73793536); //    393,216  -> total ~70.8 MB

  k_cvt<<<16384, 256, 0, stream>>>(enc, encB, 16777216);
  k_cvt<<<1536, 256, 0, stream>>>(Wih, WihB, 1572864);
  k_cvt<<<768, 256, 0, stream>>>(Whh, WhhB, 786432);
  k_transpose512<<<dim3(16,16), dim3(32,8), 0, stream>>>(We, WeT);
  k_transpose512<<<dim3(16,16), dim3(32,8), 0, stream>>>(Wd, WdT);
  k_init<<<128, 256, 0, stream>>>(h0, hf, xcat);
  k_encproj<<<dim3(256,4), 256, 0, stream>>>(encB, WeT, ep);
  k_q0<<<64, 256, 0, stream>>>(hf, WdT, ab, q);
  for (int t=0; t<NSTEP; ++t){
    k_sgh<<<2096, 256, 0, stream>>>(ep, q, av, xcat, WhhB, bhh, WihB, bih, sc, gh, gi);
    k_ctx<<<dim3(4,64), 256, 0, stream>>>(sc, encB, xcat);
    k_gictx<<<24, 256, 0, stream>>>(xcat, WihB, gi);
    k_fin<<<64, 256, 0, stream>>>(gi, gh, lng, lnb, W1, b1, W2, b2, WdT, ab,
                                  hf, xcat, q, out, t);
  }
}